// Round 2
// baseline (6941.843 us; speedup 1.0000x reference)
//
#include <hip/hip_runtime.h>
#include <hip/hip_bf16.h>

#define SEQ 118
#define YS  136   // Ybuf stride (272 B, 16B-aligned rows)
#define SQS 40    // sQP/sK stride (80 B)
#define SVS 136   // sVt stride

typedef __attribute__((ext_vector_type(8))) short short8;
typedef __attribute__((ext_vector_type(4))) float f32x4;
typedef __attribute__((ext_vector_type(4))) unsigned u32x4;

__device__ __forceinline__ f32x4 mfma16(short8 a, short8 b, f32x4 c){
  return __builtin_amdgcn_mfma_f32_16x16x32_bf16(a, b, c, 0, 0, 0);
}
__device__ __forceinline__ float bfr(float x){
  return __bfloat162float(__float2bfloat16(x));
}
__device__ __forceinline__ float rcpf(float x){ return __builtin_amdgcn_rcpf(x); }
__device__ __forceinline__ float fsilu(float z){   // z*sigmoid(z), rcp+exp2 (1-ulp parts)
  return z * rcpf(1.f + exp2f(-1.442695041f * z));
}
__device__ __forceinline__ float rsum16(float v){
  v += __shfl_xor(v,1); v += __shfl_xor(v,2); v += __shfl_xor(v,4); v += __shfl_xor(v,8);
  return v;
}
__device__ __forceinline__ float rmax16(float v){
  v = fmaxf(v, __shfl_xor(v,1)); v = fmaxf(v, __shfl_xor(v,2));
  v = fmaxf(v, __shfl_xor(v,4)); v = fmaxf(v, __shfl_xor(v,8));
  return v;
}
__device__ __forceinline__ unsigned pack_bf2(float lo, float hi){
  __hip_bfloat162 h2 = __float22bfloat162_rn(float2{lo, hi});  // packed RNE cvt
  unsigned u; __builtin_memcpy(&u, &h2, 4);   // bit_cast rejected: non-trivial copy
  return u;
}

// Pre-permuted bf16 weights (verified round 7):
//  wq/wk/wv: [h][n][k], n <-> orig col d = 4n + h (input-side to_heads)
//  w2:       [n][k'], k' = h*32 + r, dh = (r>>1)+(r&1)*16, orig k = h*32 + dh
__global__ void prep_kernel(const float* __restrict__ qkv_w,
                            const float* __restrict__ fc2_w,
                            __hip_bfloat16* __restrict__ wbf){
  int i = blockIdx.x * 256 + threadIdx.x;   // 65536 total
  int seg = i >> 14;
  int r   = i & 16383;
  int row = r >> 7;
  int k   = r & 127;
  float v;
  if (seg < 3){
    int h = row >> 5, n = row & 31;
    v = qkv_w[(seg*128 + 4*n + h)*128 + k];
  } else {
    int h = k >> 5, rr = k & 31;
    int dh = (rr >> 1) + (rr & 1)*16;
    v = fc2_w[row*128 + h*32 + dh];
  }
  wbf[i] = __float2bfloat16(v);
}

// Round 12 = round 11 with the launch-bounds fix. EMPIRICAL (round-11 counters):
// this hipcc treats __launch_bounds__ arg2 as MIN WORKGROUPS/CU (CUDA semantics),
// not waves/EU: (512,6) -> 12 waves/SIMD -> 40-VGPR cap -> 22 GB of scratch spill
// traffic. (512,3) -> 6 waves/SIMD -> ~85-VGPR cap; ypk/softmax peak (~80) fits.
// LDS 36864 allows 4 blocks/CU if the allocator lands <=64 VGPR; 3 guaranteed.
__launch_bounds__(512, 3)
__global__ void fused_kernel(const float* __restrict__ x,
                             const float* __restrict__ fc1_w, const float* __restrict__ fc1_b,
                             const float* __restrict__ qkv_b,
                             const float* __restrict__ fc2_b, const float* __restrict__ fc3_w,
                             const float* __restrict__ fc3_b,
                             const float* __restrict__ ln_g,  const float* __restrict__ ln_b,
                             const __hip_bfloat16* __restrict__ wbf,
                             float* __restrict__ out)
{
  __shared__ __align__(16) char smem[36864];
  // Region A (live only inside head loop):
  __hip_bfloat16* sQP  = (__hip_bfloat16*)(smem);           // 128 x 40   10240
  __hip_bfloat16* sK   = (__hip_bfloat16*)(smem + 10240);   // 128 x 40   10240
  __hip_bfloat16* sVt  = (__hip_bfloat16*)(smem + 20480);   //  32 x 136   8704
  // Region B (ALIASES region A; live only after head loop, wave-private rows):
  __hip_bfloat16* Ybuf = (__hip_bfloat16*)(smem);           // 128 x 136  34816
  // Persistent:
  float*          sCb  = (float*)        (smem + 34816);    // 512 f32     2048

  const __hip_bfloat16* wq  = wbf;
  const __hip_bfloat16* wk  = wbf + 16384;
  const __hip_bfloat16* wvw = wbf + 32768;
  const __hip_bfloat16* w2  = wbf + 49152;

  const int b    = blockIdx.x;
  const int tid  = threadIdx.x;
  const int wv   = tid >> 6;        // wave 0..7 -> 16-row strip
  const int lane = tid & 63;
  const int c    = lane & 15;
  const int quad = lane >> 4;
  const int arow = wv*16 + c;       // this lane's M-row for A/ay fragments

  { // sCb: fc2_b(0..127) fc3_w(128..255) ln_g(256..383) ln_b(384..511)
    int i = tid;
    if (i < 512){
      float v;
      if      (i < 128) v = fc2_b[i];
      else if (i < 256) v = fc3_w[i-128];
      else if (i < 384) v = ln_g [i-256];
      else              v = ln_b [i-384];
      sCb[i] = v;
    }
  }
  __syncthreads();

  float o1[4];

  #pragma unroll 1
  for (int p = 0; p < 2; ++p){
    // ---- A fragments for this pass (registers only) ----
    short8 afr[4];
    if (p == 0){
      float xs = (arow < SEQ) ? x[b*SEQ + arow] : 0.f;
      #pragma unroll
      for (int k4 = 0; k4 < 4; k4++){
        int d0 = k4*32 + quad*8;
        short8 fr;
        #pragma unroll
        for (int i = 0; i < 8; i++){
          float z = xs * fc1_w[d0+i] + fc1_b[d0+i];
          float v = fsilu(z);
          if (arow >= SEQ) v = 0.f;             // pad rows exact zero
          fr[i] = (short)__builtin_bit_cast(unsigned short, __float2bfloat16(v));
        }
        afr[k4] = fr;
      }
    } else {
      #pragma unroll
      for (int k4 = 0; k4 < 4; k4++){
        short8 fr = *(const short8*)(Ybuf + arow*YS + k4*32 + quad*8);
        if (arow >= SEQ) fr = (short8){0,0,0,0,0,0,0,0};  // NaN guard for V path
        afr[k4] = fr;
      }
      __syncthreads();   // all waves' afr reads done before region A is overwritten
    }

    unsigned ypk[4][4];   // per-head packed Y (y0,y1) pairs, statically indexed

    #pragma unroll
    for (int h = 0; h < 4; ++h){
      const float invf = exp2f((float)(4*c + h) * (-0.20762050593045f)); // 10000^(-d/64)

      { // ---- Q & K head GEMMs + RoPE -> sQP / sK (packed pair k-order) ----
        // Q written pre-scaled by KSC = 1/sqrt(32)/ln2: softmax is pure exp2.
        const __hip_bfloat16* wpq = wq + (h*32 + c)*128 + quad*8;
        const __hip_bfloat16* wpk = wk + (h*32 + c)*128 + quad*8;
        f32x4 q0={0,0,0,0}, q1={0,0,0,0}, k0={0,0,0,0}, k1={0,0,0,0};
        #pragma unroll
        for (int k4 = 0; k4 < 4; k4++){
          short8 bq0 = *(const short8*)(wpq + k4*32);
          short8 bq1 = *(const short8*)(wpq + 2048 + k4*32);
          short8 bk0 = *(const short8*)(wpk + k4*32);
          short8 bk1 = *(const short8*)(wpk + 2048 + k4*32);
          q0 = mfma16(afr[k4], bq0, q0);
          q1 = mfma16(afr[k4], bq1, q1);
          k0 = mfma16(afr[k4], bk0, k0);
          k1 = mfma16(afr[k4], bk1, k1);
        }
        const float KSC = 0.25500526963f;   // (1/sqrt(32)) * (1/ln2)
        float bQ0 = qkv_b[      4*c + h], bQ1 = qkv_b[ 64 + 4*c + h];
        float bK0 = qkv_b[128 + 4*c + h], bK1 = qkv_b[192 + 4*c + h];
        #pragma unroll
        for (int j = 0; j < 4; j++){
          int s = wv*16 + quad*4 + j;
          float ang = (float)s * invf;
          float cv = bfr(__cosf(ang)), sv = bfr(__sinf(ang));
          float cvq = cv*KSC, svq = sv*KSC;
          float xq1 = q0[j] + bQ0, xq2 = q1[j] + bQ1;
          float xk1 = k0[j] + bK0, xk2 = k1[j] + bK1;
          *(unsigned*)(sQP + s*SQS + 2*c) = pack_bf2( xq1*cvq + xq2*svq, -xq1*svq + xq2*cvq);
          *(unsigned*)(sK  + s*SQS + 2*c) = pack_bf2( xk1*cv  + xk2*sv , -xk1*sv  + xk2*cv );
        }
      }
      { // ---- V head GEMM -> transposed sVt[dh][s] ----
        const __hip_bfloat16* wpv = wvw + (h*32 + c)*128 + quad*8;
        f32x4 v0={0,0,0,0}, v1={0,0,0,0};
        #pragma unroll
        for (int k4 = 0; k4 < 4; k4++){
          short8 b0 = *(const short8*)(wpv + k4*32);
          short8 b1 = *(const short8*)(wpv + 2048 + k4*32);
          v0 = mfma16(afr[k4], b0, v0);
          v1 = mfma16(afr[k4], b1, v1);
        }
        float bV0 = qkv_b[256 + 4*c + h], bV1 = qkv_b[320 + 4*c + h];
        int s0 = wv*16 + quad*4;
        *(unsigned*)(sVt + (c   )*SVS + s0    ) = pack_bf2(v0[0]+bV0, v0[1]+bV0);
        *(unsigned*)(sVt + (c   )*SVS + s0 + 2) = pack_bf2(v0[2]+bV0, v0[3]+bV0);
        *(unsigned*)(sVt + (c+16)*SVS + s0    ) = pack_bf2(v1[0]+bV1, v1[1]+bV1);
        *(unsigned*)(sVt + (c+16)*SVS + s0 + 2) = pack_bf2(v1[2]+bV1, v1[3]+bV1);
      }
      __syncthreads();   // K/Vt visible to all waves

      // ---- QK^T (causal tile skip) + softmax (exp2 domain, Q pre-scaled) ----
      short8 aq = *(const short8*)(sQP + arow*SQS + quad*8);
      f32x4 sc[8];
      #pragma unroll
      for (int t = 0; t < 8; t++){
        sc[t] = (f32x4){0.f,0.f,0.f,0.f};
        if (t <= wv){
          short8 bk = *(const short8*)(sK + (t*16 + c)*SQS + quad*8);
          f32x4 z = {0,0,0,0};
          sc[t] = mfma16(aq, bk, z);
        }
      }
      float rnorm[4];
      #pragma unroll
      for (int j = 0; j < 4; j++){
        float mx = -3.0e38f;
        #pragma unroll
        for (int t = 0; t < 8; t++){
          if (t < wv){                            // sub-diagonal: always valid
            mx = fmaxf(mx, sc[t][j]);
          } else if (t == wv){                    // diagonal tile: in-tile mask
            float v = (c <= quad*4 + j) ? sc[t][j] : -1.0e9f;
            sc[t][j] = v;
            mx = fmaxf(mx, v);
          }
        }
        mx = rmax16(mx);
        float sum = 0.f;
        #pragma unroll
        for (int t = 0; t < 8; t++) if (t <= wv){
          float e = exp2f(sc[t][j] - mx); sc[t][j] = e; sum += e;
        }
        sum = rsum16(sum);
        rnorm[j] = rcpf(sum);                     // applied to y after PV
      }

      // ---- pack P to bf16 pairs (frees the 32-reg sc block before PV) ----
      u32x4 pp0, pp1, pp2, pp3;
      #pragma unroll
      for (int j = 0; j < 4; j++){
        pp0[j] = pack_bf2(sc[0][j], sc[1][j]);
        pp1[j] = pack_bf2(sc[2][j], sc[3][j]);
        pp2[j] = pack_bf2(sc[4][j], sc[5][j]);
        pp3[j] = pack_bf2(sc[6][j], sc[7][j]);
      }

      // ---- P@V in 32-k quarters through sQP (wave-private; Q is dead) ----
      f32x4 y0 = {0,0,0,0}, y1 = {0,0,0,0};
      auto pv_quarter = [&](int qt, u32x4 pq){
        int s0 = wv*16 + quad*4;
        #pragma unroll
        for (int j = 0; j < 4; j++){
          unsigned u = pq[j];
          *(unsigned short*)(sQP + (s0+j)*SQS + c     ) = (unsigned short)(u & 0xffffu);
          *(unsigned short*)(sQP + (s0+j)*SQS + 16 + c) = (unsigned short)(u >> 16);
        }
        short8 ap  = *(const short8*)(sQP + arow*SQS + quad*8);
        short8 bv0 = *(const short8*)(sVt + (c   )*SVS + qt*32 + quad*8);
        short8 bv1 = *(const short8*)(sVt + (c+16)*SVS + qt*32 + quad*8);
        y0 = mfma16(ap, bv0, y0);
        y1 = mfma16(ap, bv1, y1);
      };
      int qmax = wv >> 1;
      pv_quarter(0, pp0);
      if (qmax >= 1) pv_quarter(1, pp1);
      if (qmax >= 2) pv_quarter(2, pp2);
      if (qmax >= 3) pv_quarter(3, pp3);

      // ---- Y stays in registers this head (normalized, packed bf16) ----
      #pragma unroll
      for (int j = 0; j < 4; j++)
        ypk[h][j] = pack_bf2(y0[j]*rnorm[j], y1[j]*rnorm[j]);

      __syncthreads();   // all K/Vt reads done; region A free for next head / Ybuf
    }

    { // ---- materialize Ybuf (aliases dead region A; wave-private rows) ----
      int s0 = wv*16 + quad*4;
      #pragma unroll
      for (int h = 0; h < 4; ++h){
        #pragma unroll
        for (int j = 0; j < 4; j++)
          if (s0 + j < SEQ)
            *(unsigned*)(Ybuf + (s0+j)*YS + h*32 + 2*c) = ypk[h][j];
      }
    }

    // ================= FC2 (once per pass) + silu + LN / readout ==========
    short8 ay[4];
    #pragma unroll
    for (int k4 = 0; k4 < 4; k4++)
      ay[k4] = *(const short8*)(Ybuf + arow*YS + k4*32 + quad*8);
    f32x4 xx[8];
    f32x4 S1 = {0,0,0,0}, S2 = {0,0,0,0}, S3 = {0,0,0,0};
    #pragma unroll 1
    for (int t = 0; t < 8; t++){
      f32x4 acc = {0,0,0,0};
      #pragma unroll
      for (int k4 = 0; k4 < 4; k4++){
        short8 bw = *(const short8*)(w2 + (t*16 + c)*128 + k4*32 + quad*8);
        acc = mfma16(ay[k4], bw, acc);
      }
      float bias = sCb[t*16 + c];
      float w3   = sCb[128 + t*16 + c];
      #pragma unroll
      for (int j = 0; j < 4; j++){
        float v = fsilu(acc[j] + bias);
        xx[t][j] = v;
        S1[j] += v; S2[j] += v*v; S3[j] += v*w3;
      }
    }
    #pragma unroll
    for (int j = 0; j < 4; j++){
      float s1 = rsum16(S1[j]), s2 = rsum16(S2[j]), s3 = rsum16(S3[j]);
      int s = wv*16 + quad*4 + j;
      if (p == 0){
        float mu  = s1 * (1.f/128.f);
        float var = fmaxf(s2 * (1.f/128.f) - mu*mu, 0.f);
        float rs  = rsqrtf(var + 1e-5f);
        if (s < SEQ){
          #pragma unroll
          for (int t = 0; t < 8; t++){
            int d = t*16 + c;
            Ybuf[s*YS + d] = __float2bfloat16((xx[t][j] - mu)*rs*sCb[256+d] + sCb[384+d]);
          }
        }
        o1[j] = s3;                        // x1 . fc3_w residual readout
      } else {
        if (c == 0 && s < SEQ) out[b*SEQ + s] = o1[j] + s3 + fc3_b[0];
      }
    }
    // no trailing barrier: LN writes / pass-1 afr reads are wave-private rows;
    // region A reuse in pass 1 is fenced by the post-afr __syncthreads above.
  }
}

extern "C" void kernel_launch(void* const* d_in, const int* in_sizes, int n_in,
                              void* d_out, int out_size, void* d_ws, size_t ws_size,
                              hipStream_t stream){
  const float* x     = (const float*)d_in[0];
  const float* fc1_w = (const float*)d_in[1];
  const float* fc1_b = (const float*)d_in[2];
  const float* qkv_w = (const float*)d_in[3];
  const float* qkv_b = (const float*)d_in[4];
  const float* fc2_w = (const float*)d_in[5];
  const float* fc2_b = (const float*)d_in[6];
  const float* fc3_w = (const float*)d_in[7];
  const float* fc3_b = (const float*)d_in[8];
  const float* ln_g  = (const float*)d_in[9];
  const float* ln_b  = (const float*)d_in[10];

  __hip_bfloat16* wbf = (__hip_bfloat16*)d_ws;   // 65536 bf16 = 128 KB
  prep_kernel<<<256, 256, 0, stream>>>(qkv_w, fc2_w, wbf);

  const int B = in_sizes[0] / SEQ;               // 8192
  fused_kernel<<<B, 512, 0, stream>>>(x, fc1_w, fc1_b, qkv_b, fc2_b, fc3_w, fc3_b,
                                      ln_g, ln_b, wbf, (float*)d_out);
}

// Round 3
// 3211.578 us; speedup vs baseline: 2.1615x; 2.1615x over previous
//
#include <hip/hip_runtime.h>
#include <hip/hip_bf16.h>

#define SEQ 118
#define YS  136   // Ybuf stride (272 B, 16B-aligned rows)
#define SQS 40    // sQP/sK stride (80 B)
#define SVS 136   // sVt stride

typedef __attribute__((ext_vector_type(8))) short short8;
typedef __attribute__((ext_vector_type(4))) float f32x4;
typedef __attribute__((ext_vector_type(4))) unsigned u32x4;

__device__ __forceinline__ f32x4 mfma16(short8 a, short8 b, f32x4 c){
  return __builtin_amdgcn_mfma_f32_16x16x32_bf16(a, b, c, 0, 0, 0);
}
__device__ __forceinline__ float bfr(float x){
  return __bfloat162float(__float2bfloat16(x));
}
__device__ __forceinline__ float rcpf(float x){ return __builtin_amdgcn_rcpf(x); }
__device__ __forceinline__ float fsilu(float z){   // z*sigmoid(z), rcp+exp2 (1-ulp parts)
  return z * rcpf(1.f + exp2f(-1.442695041f * z));
}
__device__ __forceinline__ float rsum16(float v){
  v += __shfl_xor(v,1); v += __shfl_xor(v,2); v += __shfl_xor(v,4); v += __shfl_xor(v,8);
  return v;
}
__device__ __forceinline__ float rmax16(float v){
  v = fmaxf(v, __shfl_xor(v,1)); v = fmaxf(v, __shfl_xor(v,2));
  v = fmaxf(v, __shfl_xor(v,4)); v = fmaxf(v, __shfl_xor(v,8));
  return v;
}
__device__ __forceinline__ unsigned pack_bf2(float lo, float hi){
  __hip_bfloat162 h2 = __float22bfloat162_rn(float2{lo, hi});  // packed RNE cvt
  unsigned u; __builtin_memcpy(&u, &h2, 4);   // bit_cast rejected: non-trivial copy
  return u;
}

// Pre-permuted bf16 weights (verified round 7):
//  wq/wk/wv: [h][n][k], n <-> orig col d = 4n + h (input-side to_heads)
//  w2:       [n][k'], k' = h*32 + r, dh = (r>>1)+(r&1)*16, orig k = h*32 + dh
__global__ void prep_kernel(const float* __restrict__ qkv_w,
                            const float* __restrict__ fc2_w,
                            __hip_bfloat16* __restrict__ wbf){
  int i = blockIdx.x * 256 + threadIdx.x;   // 65536 total
  int seg = i >> 14;
  int r   = i & 16383;
  int row = r >> 7;
  int k   = r & 127;
  float v;
  if (seg < 3){
    int h = row >> 5, n = row & 31;
    v = qkv_w[(seg*128 + 4*n + h)*128 + k];
  } else {
    int h = k >> 5, rr = k & 31;
    int dh = (rr >> 1) + (rr & 1)*16;
    v = fc2_w[row*128 + h*32 + dh];
  }
  wbf[i] = __float2bfloat16(v);
}

// Round 13 = round-10 structure (the proven 2530 us kernel) with two fixes:
// 1) __launch_bounds__(512, 2): LDS (63,328 B) limits residency to 2 blocks/CU
//    regardless, so the old (512,4) 64-VGPR cap bought nothing and cost
//    ~177 MB/dispatch of scratch spill traffic (round-10 WRITE_SIZE) plus
//    serialized weight loads. 2 blocks/CU affords 128 VGPR -> no spill.
// 2) B-fragment loads explicitly hoisted into static arrays before each MFMA
//    chain (Q/K: 16 frags, V: 8, FC2: 4/t with unroll 2) so the ~200-cycle
//    L2 latency of the weight loads overlaps MFMA issue instead of serializing.
// EMPIRICAL (rounds 11-12): this hipcc treats __launch_bounds__ arg2 as MIN
// WORKGROUPS/CU (CUDA semantics): (512,6)->40 VGPR cap, (512,3)->84. Register-
// held-Y structure spills even at 84; reverted to per-head Ybuf writes.
__launch_bounds__(512, 2)
__global__ void fused_kernel(const float* __restrict__ x,
                             const float* __restrict__ fc1_w, const float* __restrict__ fc1_b,
                             const float* __restrict__ qkv_b,
                             const float* __restrict__ fc2_b, const float* __restrict__ fc3_w,
                             const float* __restrict__ fc3_b,
                             const float* __restrict__ ln_g,  const float* __restrict__ ln_b,
                             const __hip_bfloat16* __restrict__ wbf,
                             float* __restrict__ out)
{
  __shared__ __align__(16) char smem[63328];
  __hip_bfloat16* Ybuf = (__hip_bfloat16*)(smem);           // 118 x 136  32096
  __hip_bfloat16* sQP  = (__hip_bfloat16*)(smem + 32096);   // 128 x 40   10240
  __hip_bfloat16* sK   = (__hip_bfloat16*)(smem + 42336);   // 128 x 40   10240
  __hip_bfloat16* sVt  = (__hip_bfloat16*)(smem + 52576);   //  32 x 136   8704
  float*          sCb  = (float*)        (smem + 61280);    // 512 f32     2048

  const __hip_bfloat16* wq  = wbf;
  const __hip_bfloat16* wk  = wbf + 16384;
  const __hip_bfloat16* wvw = wbf + 32768;
  const __hip_bfloat16* w2  = wbf + 49152;

  const int b    = blockIdx.x;
  const int tid  = threadIdx.x;
  const int wv   = tid >> 6;        // wave 0..7 -> 16-row strip
  const int lane = tid & 63;
  const int c    = lane & 15;
  const int quad = lane >> 4;
  const int arow = wv*16 + c;       // this lane's M-row for A/ay fragments

  { // sCb: fc2_b(0..127) fc3_w(128..255) ln_g(256..383) ln_b(384..511)
    int i = tid;
    if (i < 512){
      float v;
      if      (i < 128) v = fc2_b[i];
      else if (i < 256) v = fc3_w[i-128];
      else if (i < 384) v = ln_g [i-256];
      else              v = ln_b [i-384];
      sCb[i] = v;
    }
  }
  __syncthreads();

  float o1[4];

  #pragma unroll 1
  for (int p = 0; p < 2; ++p){
    // ---- A fragments for this pass (registers only) ----
    short8 afr[4];
    if (p == 0){
      float xs = (arow < SEQ) ? x[b*SEQ + arow] : 0.f;
      #pragma unroll
      for (int k4 = 0; k4 < 4; k4++){
        int d0 = k4*32 + quad*8;
        short8 fr;
        #pragma unroll
        for (int i = 0; i < 8; i++){
          float z = xs * fc1_w[d0+i] + fc1_b[d0+i];
          float v = fsilu(z);
          if (arow >= SEQ) v = 0.f;             // pad rows exact zero
          fr[i] = (short)__builtin_bit_cast(unsigned short, __float2bfloat16(v));
        }
        afr[k4] = fr;
      }
    } else {
      #pragma unroll
      for (int k4 = 0; k4 < 4; k4++){
        short8 fr = *(const short8*)(Ybuf + arow*YS + k4*32 + quad*8);
        if (arow >= SEQ) fr = (short8){0,0,0,0,0,0,0,0};  // NaN guard for V path
        afr[k4] = fr;
      }
    }

    #pragma unroll 1
    for (int h = 0; h < 4; ++h){
      const float invf = exp2f((float)(4*c + h) * (-0.20762050593045f)); // 10000^(-d/64)

      { // ---- Q & K head GEMMs + RoPE -> sQP / sK (packed pair k-order) ----
        // Q written pre-scaled by KSC = 1/sqrt(32)/ln2: softmax is pure exp2.
        const __hip_bfloat16* wpq = wq + (h*32 + c)*128 + quad*8;
        const __hip_bfloat16* wpk = wk + (h*32 + c)*128 + quad*8;
        short8 Bq0[4], Bq1[4], Bk0[4], Bk1[4];   // hoisted: 16 loads in flight
        #pragma unroll
        for (int k4 = 0; k4 < 4; k4++){
          Bq0[k4] = *(const short8*)(wpq + k4*32);
          Bq1[k4] = *(const short8*)(wpq + 2048 + k4*32);
          Bk0[k4] = *(const short8*)(wpk + k4*32);
          Bk1[k4] = *(const short8*)(wpk + 2048 + k4*32);
        }
        f32x4 q0={0,0,0,0}, q1={0,0,0,0}, k0={0,0,0,0}, k1={0,0,0,0};
        #pragma unroll
        for (int k4 = 0; k4 < 4; k4++){
          q0 = mfma16(afr[k4], Bq0[k4], q0);
          q1 = mfma16(afr[k4], Bq1[k4], q1);
          k0 = mfma16(afr[k4], Bk0[k4], k0);
          k1 = mfma16(afr[k4], Bk1[k4], k1);
        }
        const float KSC = 0.25500526963f;   // (1/sqrt(32)) * (1/ln2)
        float bQ0 = qkv_b[      4*c + h], bQ1 = qkv_b[ 64 + 4*c + h];
        float bK0 = qkv_b[128 + 4*c + h], bK1 = qkv_b[192 + 4*c + h];
        #pragma unroll
        for (int j = 0; j < 4; j++){
          int s = wv*16 + quad*4 + j;
          float ang = (float)s * invf;
          float cv = bfr(__cosf(ang)), sv = bfr(__sinf(ang));
          float cvq = cv*KSC, svq = sv*KSC;
          float xq1 = q0[j] + bQ0, xq2 = q1[j] + bQ1;
          float xk1 = k0[j] + bK0, xk2 = k1[j] + bK1;
          *(unsigned*)(sQP + s*SQS + 2*c) = pack_bf2( xq1*cvq + xq2*svq, -xq1*svq + xq2*cvq);
          *(unsigned*)(sK  + s*SQS + 2*c) = pack_bf2( xk1*cv  + xk2*sv , -xk1*sv  + xk2*cv );
        }
      }
      { // ---- V head GEMM -> transposed sVt[dh][s] ----
        const __hip_bfloat16* wpv = wvw + (h*32 + c)*128 + quad*8;
        short8 Bv0[4], Bv1[4];                   // hoisted: 8 loads in flight
        #pragma unroll
        for (int k4 = 0; k4 < 4; k4++){
          Bv0[k4] = *(const short8*)(wpv + k4*32);
          Bv1[k4] = *(const short8*)(wpv + 2048 + k4*32);
        }
        f32x4 v0={0,0,0,0}, v1={0,0,0,0};
        #pragma unroll
        for (int k4 = 0; k4 < 4; k4++){
          v0 = mfma16(afr[k4], Bv0[k4], v0);
          v1 = mfma16(afr[k4], Bv1[k4], v1);
        }
        float bV0 = qkv_b[256 + 4*c + h], bV1 = qkv_b[320 + 4*c + h];
        int s0 = wv*16 + quad*4;
        *(unsigned*)(sVt + (c   )*SVS + s0    ) = pack_bf2(v0[0]+bV0, v0[1]+bV0);
        *(unsigned*)(sVt + (c   )*SVS + s0 + 2) = pack_bf2(v0[2]+bV0, v0[3]+bV0);
        *(unsigned*)(sVt + (c+16)*SVS + s0    ) = pack_bf2(v1[0]+bV1, v1[1]+bV1);
        *(unsigned*)(sVt + (c+16)*SVS + s0 + 2) = pack_bf2(v1[2]+bV1, v1[3]+bV1);
      }
      __syncthreads();   // K/Vt visible to all waves

      // ---- QK^T (causal tile skip) + softmax (exp2 domain, Q pre-scaled) ----
      short8 aq = *(const short8*)(sQP + arow*SQS + quad*8);
      f32x4 sc[8];
      #pragma unroll
      for (int t = 0; t < 8; t++){
        sc[t] = (f32x4){0.f,0.f,0.f,0.f};
        if (t <= wv){
          short8 bk = *(const short8*)(sK + (t*16 + c)*SQS + quad*8);
          f32x4 z = {0,0,0,0};
          sc[t] = mfma16(aq, bk, z);
        }
      }
      float rnorm[4];
      #pragma unroll
      for (int j = 0; j < 4; j++){
        float mx = -3.0e38f;
        #pragma unroll
        for (int t = 0; t < 8; t++){
          if (t < wv){                            // sub-diagonal: always valid
            mx = fmaxf(mx, sc[t][j]);
          } else if (t == wv){                    // diagonal tile: in-tile mask
            float v = (c <= quad*4 + j) ? sc[t][j] : -1.0e9f;
            sc[t][j] = v;
            mx = fmaxf(mx, v);
          }
        }
        mx = rmax16(mx);
        float sum = 0.f;
        #pragma unroll
        for (int t = 0; t < 8; t++) if (t <= wv){
          float e = exp2f(sc[t][j] - mx); sc[t][j] = e; sum += e;
        }
        sum = rsum16(sum);
        rnorm[j] = rcpf(sum);                     // applied to y after PV
      }

      // ---- P@V in 32-k quarters through sQP (wave-private; Q is dead) ----
      f32x4 y0 = {0,0,0,0}, y1 = {0,0,0,0};
      auto pv_quarter = [&](int qt, f32x4 pa, f32x4 pb){
        int s0 = wv*16 + quad*4;
        #pragma unroll
        for (int j = 0; j < 4; j++){
          sQP[(s0+j)*SQS + c     ] = __float2bfloat16(pa[j]);
          sQP[(s0+j)*SQS + 16 + c] = __float2bfloat16(pb[j]);
        }
        short8 ap  = *(const short8*)(sQP + arow*SQS + quad*8);
        short8 bv0 = *(const short8*)(sVt + (c   )*SVS + qt*32 + quad*8);
        short8 bv1 = *(const short8*)(sVt + (c+16)*SVS + qt*32 + quad*8);
        y0 = mfma16(ap, bv0, y0);
        y1 = mfma16(ap, bv1, y1);
      };
      int qmax = wv >> 1;
      pv_quarter(0, sc[0], sc[1]);
      if (qmax >= 1) pv_quarter(1, sc[2], sc[3]);
      if (qmax >= 2) pv_quarter(2, sc[4], sc[5]);
      if (qmax >= 3) pv_quarter(3, sc[6], sc[7]);
      #pragma unroll
      for (int j = 0; j < 4; j++){ y0[j] *= rnorm[j]; y1[j] *= rnorm[j]; }

      { // ---- Y -> Ybuf at this head's k'-slice (guarded: 118 rows only) ----
        int s0 = wv*16 + quad*4;
        #pragma unroll
        for (int j = 0; j < 4; j++)
          if (s0 + j < SEQ)
            *(unsigned*)(Ybuf + (s0+j)*YS + h*32 + 2*c) = pack_bf2(y0[j], y1[j]);
      }
      __syncthreads();   // all reads of K/Vt done; also fences Ybuf for FC2
    }

    // ================= FC2 (once per pass) + silu + LN / readout ==========
    short8 ay[4];
    #pragma unroll
    for (int k4 = 0; k4 < 4; k4++)
      ay[k4] = *(const short8*)(Ybuf + arow*YS + k4*32 + quad*8);
    f32x4 xx[8];
    f32x4 S1 = {0,0,0,0}, S2 = {0,0,0,0}, S3 = {0,0,0,0};
    #pragma unroll 2
    for (int t = 0; t < 8; t++){
      short8 Bw[4];                              // hoisted: 4 loads in flight
      #pragma unroll
      for (int k4 = 0; k4 < 4; k4++)
        Bw[k4] = *(const short8*)(w2 + (t*16 + c)*128 + k4*32 + quad*8);
      f32x4 acc = {0,0,0,0};
      #pragma unroll
      for (int k4 = 0; k4 < 4; k4++)
        acc = mfma16(ay[k4], Bw[k4], acc);
      float bias = sCb[t*16 + c];
      float w3   = sCb[128 + t*16 + c];
      #pragma unroll
      for (int j = 0; j < 4; j++){
        float v = fsilu(acc[j] + bias);
        xx[t][j] = v;
        S1[j] += v; S2[j] += v*v; S3[j] += v*w3;
      }
    }
    #pragma unroll
    for (int j = 0; j < 4; j++){
      float s1 = rsum16(S1[j]), s2 = rsum16(S2[j]), s3 = rsum16(S3[j]);
      int s = wv*16 + quad*4 + j;
      if (p == 0){
        float mu  = s1 * (1.f/128.f);
        float var = fmaxf(s2 * (1.f/128.f) - mu*mu, 0.f);
        float rs  = rsqrtf(var + 1e-5f);
        if (s < SEQ){
          #pragma unroll
          for (int t = 0; t < 8; t++){
            int d = t*16 + c;
            Ybuf[s*YS + d] = __float2bfloat16((xx[t][j] - mu)*rs*sCb[256+d] + sCb[384+d]);
          }
        }
        o1[j] = s3;                        // x1 . fc3_w residual readout
      } else {
        if (c == 0 && s < SEQ) out[b*SEQ + s] = o1[j] + s3 + fc3_b[0];
      }
    }
    if (p == 0) __syncthreads();   // fence LN writes before pass-1 afr reads
  }
}

extern "C" void kernel_launch(void* const* d_in, const int* in_sizes, int n_in,
                              void* d_out, int out_size, void* d_ws, size_t ws_size,
                              hipStream_t stream){
  const float* x     = (const float*)d_in[0];
  const float* fc1_w = (const float*)d_in[1];
  const float* fc1_b = (const float*)d_in[2];
  const float* qkv_w = (const float*)d_in[3];
  const float* qkv_b = (const float*)d_in[4];
  const float* fc2_w = (const float*)d_in[5];
  const float* fc2_b = (const float*)d_in[6];
  const float* fc3_w = (const float*)d_in[7];
  const float* fc3_b = (const float*)d_in[8];
  const float* ln_g  = (const float*)d_in[9];
  const float* ln_b  = (const float*)d_in[10];

  __hip_bfloat16* wbf = (__hip_bfloat16*)d_ws;   // 65536 bf16 = 128 KB
  prep_kernel<<<256, 256, 0, stream>>>(qkv_w, fc2_w, wbf);

  const int B = in_sizes[0] / SEQ;               // 8192
  fused_kernel<<<B, 512, 0, stream>>>(x, fc1_w, fc1_b, qkv_b, fc2_b, fc3_w, fc3_b,
                                      ln_g, ln_b, wbf, (float*)d_out);
}

// Round 4
// 3168.552 us; speedup vs baseline: 2.1909x; 1.0136x over previous
//
#include <hip/hip_runtime.h>
#include <hip/hip_bf16.h>

#define SEQ 118
#define YS  136   // Ybuf stride (272 B, 16B-aligned rows)
#define SQS 40    // sQP/sK stride (80 B)
#define SVS 136   // sVt stride

typedef __attribute__((ext_vector_type(8))) short short8;
typedef __attribute__((ext_vector_type(4))) float f32x4;

__device__ __forceinline__ f32x4 mfma16(short8 a, short8 b, f32x4 c){
  return __builtin_amdgcn_mfma_f32_16x16x32_bf16(a, b, c, 0, 0, 0);
}
__device__ __forceinline__ float bfr(float x){
  return __bfloat162float(__float2bfloat16(x));
}
__device__ __forceinline__ float rcpf(float x){ return __builtin_amdgcn_rcpf(x); }
__device__ __forceinline__ float fsilu(float z){   // z*sigmoid(z), rcp+exp2 (1-ulp parts)
  return z * rcpf(1.f + exp2f(-1.442695041f * z));
}
__device__ __forceinline__ float rsum16(float v){
  v += __shfl_xor(v,1); v += __shfl_xor(v,2); v += __shfl_xor(v,4); v += __shfl_xor(v,8);
  return v;
}
__device__ __forceinline__ float rmax16(float v){
  v = fmaxf(v, __shfl_xor(v,1)); v = fmaxf(v, __shfl_xor(v,2));
  v = fmaxf(v, __shfl_xor(v,4)); v = fmaxf(v, __shfl_xor(v,8));
  return v;
}
__device__ __forceinline__ unsigned pack_bf2(float lo, float hi){
  __hip_bfloat162 h2 = __float22bfloat162_rn(float2{lo, hi});  // packed RNE cvt
  unsigned u; __builtin_memcpy(&u, &h2, 4);   // bit_cast rejected: non-trivial copy
  return u;
}

// Pre-permuted bf16 weights (verified round 7):
//  wq/wk/wv: [h][n][k], n <-> orig col d = 4n + h (input-side to_heads)
//  w2:       [n][k'], k' = h*32 + r, dh = (r>>1)+(r&1)*16, orig k = h*32 + dh
__global__ void prep_kernel(const float* __restrict__ qkv_w,
                            const float* __restrict__ fc2_w,
                            __hip_bfloat16* __restrict__ wbf){
  int i = blockIdx.x * 256 + threadIdx.x;   // 65536 total
  int seg = i >> 14;
  int r   = i & 16383;
  int row = r >> 7;
  int k   = r & 127;
  float v;
  if (seg < 3){
    int h = row >> 5, n = row & 31;
    v = qkv_w[(seg*128 + 4*n + h)*128 + k];
  } else {
    int h = k >> 5, rr = k & 31;
    int dh = (rr >> 1) + (rr & 1)*16;
    v = fc2_w[row*128 + h*32 + dh];
  }
  wbf[i] = __float2bfloat16(v);
}

// Round 14 = round-10 body EXACTLY (no hoist arrays), only launch-bounds changed
// to (512, 2). Register model refined over rounds 11-13 (rocprof evidence):
//  - arg2 is MIN WORKGROUPS/CU (CUDA semantics): cap = 512/(2*arg2) arch VGPRs.
//  - residency needs arch + acc <= 128 total for 2 blocks/CU.
//  - round 10: (512,4) -> arch cap 64: 2 blocks BUT ~42 B/thread scratch spill
//    (177 MB WRITE_SIZE) serialized on the critical path.
//  - round 13: hoist arrays -> arch 92 + acc ~40 > 128 -> 1 block/CU, slower.
// This round: cap 128, no hand hoists -> compiler keeps the former spills in
// regs (~+10 arch), total stays under 128 -> 2 blocks AND no scratch.
__launch_bounds__(512, 2)
__global__ void fused_kernel(const float* __restrict__ x,
                             const float* __restrict__ fc1_w, const float* __restrict__ fc1_b,
                             const float* __restrict__ qkv_b,
                             const float* __restrict__ fc2_b, const float* __restrict__ fc3_w,
                             const float* __restrict__ fc3_b,
                             const float* __restrict__ ln_g,  const float* __restrict__ ln_b,
                             const __hip_bfloat16* __restrict__ wbf,
                             float* __restrict__ out)
{
  __shared__ __align__(16) char smem[63328];
  __hip_bfloat16* Ybuf = (__hip_bfloat16*)(smem);           // 118 x 136  32096
  __hip_bfloat16* sQP  = (__hip_bfloat16*)(smem + 32096);   // 128 x 40   10240
  __hip_bfloat16* sK   = (__hip_bfloat16*)(smem + 42336);   // 128 x 40   10240
  __hip_bfloat16* sVt  = (__hip_bfloat16*)(smem + 52576);   //  32 x 136   8704
  float*          sCb  = (float*)        (smem + 61280);    // 512 f32     2048

  const __hip_bfloat16* wq  = wbf;
  const __hip_bfloat16* wk  = wbf + 16384;
  const __hip_bfloat16* wvw = wbf + 32768;
  const __hip_bfloat16* w2  = wbf + 49152;

  const int b    = blockIdx.x;
  const int tid  = threadIdx.x;
  const int wv   = tid >> 6;        // wave 0..7 -> 16-row strip
  const int lane = tid & 63;
  const int c    = lane & 15;
  const int quad = lane >> 4;
  const int arow = wv*16 + c;       // this lane's M-row for A/ay fragments

  { // sCb: fc2_b(0..127) fc3_w(128..255) ln_g(256..383) ln_b(384..511)
    int i = tid;
    if (i < 512){
      float v;
      if      (i < 128) v = fc2_b[i];
      else if (i < 256) v = fc3_w[i-128];
      else if (i < 384) v = ln_g [i-256];
      else              v = ln_b [i-384];
      sCb[i] = v;
    }
  }
  __syncthreads();

  float o1[4];

  #pragma unroll 1
  for (int p = 0; p < 2; ++p){
    // ---- A fragments for this pass (registers only) ----
    short8 afr[4];
    if (p == 0){
      float xs = (arow < SEQ) ? x[b*SEQ + arow] : 0.f;
      #pragma unroll
      for (int k4 = 0; k4 < 4; k4++){
        int d0 = k4*32 + quad*8;
        short8 fr;
        #pragma unroll
        for (int i = 0; i < 8; i++){
          float z = xs * fc1_w[d0+i] + fc1_b[d0+i];
          float v = fsilu(z);
          if (arow >= SEQ) v = 0.f;             // pad rows exact zero
          fr[i] = (short)__builtin_bit_cast(unsigned short, __float2bfloat16(v));
        }
        afr[k4] = fr;
      }
    } else {
      #pragma unroll
      for (int k4 = 0; k4 < 4; k4++){
        short8 fr = *(const short8*)(Ybuf + arow*YS + k4*32 + quad*8);
        if (arow >= SEQ) fr = (short8){0,0,0,0,0,0,0,0};  // NaN guard for V path
        afr[k4] = fr;
      }
    }

    #pragma unroll 1
    for (int h = 0; h < 4; ++h){
      const float invf = exp2f((float)(4*c + h) * (-0.20762050593045f)); // 10000^(-d/64)

      { // ---- Q & K head GEMMs + RoPE -> sQP / sK (packed pair k-order) ----
        // Q written pre-scaled by KSC = 1/sqrt(32)/ln2: softmax is pure exp2.
        const __hip_bfloat16* wpq = wq + (h*32 + c)*128 + quad*8;
        const __hip_bfloat16* wpk = wk + (h*32 + c)*128 + quad*8;
        f32x4 q0={0,0,0,0}, q1={0,0,0,0}, k0={0,0,0,0}, k1={0,0,0,0};
        #pragma unroll
        for (int k4 = 0; k4 < 4; k4++){
          short8 bq0 = *(const short8*)(wpq + k4*32);
          short8 bq1 = *(const short8*)(wpq + 2048 + k4*32);
          short8 bk0 = *(const short8*)(wpk + k4*32);
          short8 bk1 = *(const short8*)(wpk + 2048 + k4*32);
          q0 = mfma16(afr[k4], bq0, q0);
          q1 = mfma16(afr[k4], bq1, q1);
          k0 = mfma16(afr[k4], bk0, k0);
          k1 = mfma16(afr[k4], bk1, k1);
        }
        const float KSC = 0.25500526963f;   // (1/sqrt(32)) * (1/ln2)
        float bQ0 = qkv_b[      4*c + h], bQ1 = qkv_b[ 64 + 4*c + h];
        float bK0 = qkv_b[128 + 4*c + h], bK1 = qkv_b[192 + 4*c + h];
        #pragma unroll
        for (int j = 0; j < 4; j++){
          int s = wv*16 + quad*4 + j;
          float ang = (float)s * invf;
          float cv = bfr(__cosf(ang)), sv = bfr(__sinf(ang));
          float cvq = cv*KSC, svq = sv*KSC;
          float xq1 = q0[j] + bQ0, xq2 = q1[j] + bQ1;
          float xk1 = k0[j] + bK0, xk2 = k1[j] + bK1;
          *(unsigned*)(sQP + s*SQS + 2*c) = pack_bf2( xq1*cvq + xq2*svq, -xq1*svq + xq2*cvq);
          *(unsigned*)(sK  + s*SQS + 2*c) = pack_bf2( xk1*cv  + xk2*sv , -xk1*sv  + xk2*cv );
        }
      }
      { // ---- V head GEMM -> transposed sVt[dh][s] ----
        const __hip_bfloat16* wpv = wvw + (h*32 + c)*128 + quad*8;
        f32x4 v0={0,0,0,0}, v1={0,0,0,0};
        #pragma unroll
        for (int k4 = 0; k4 < 4; k4++){
          short8 b0 = *(const short8*)(wpv + k4*32);
          short8 b1 = *(const short8*)(wpv + 2048 + k4*32);
          v0 = mfma16(afr[k4], b0, v0);
          v1 = mfma16(afr[k4], b1, v1);
        }
        float bV0 = qkv_b[256 + 4*c + h], bV1 = qkv_b[320 + 4*c + h];
        int s0 = wv*16 + quad*4;
        *(unsigned*)(sVt + (c   )*SVS + s0    ) = pack_bf2(v0[0]+bV0, v0[1]+bV0);
        *(unsigned*)(sVt + (c   )*SVS + s0 + 2) = pack_bf2(v0[2]+bV0, v0[3]+bV0);
        *(unsigned*)(sVt + (c+16)*SVS + s0    ) = pack_bf2(v1[0]+bV1, v1[1]+bV1);
        *(unsigned*)(sVt + (c+16)*SVS + s0 + 2) = pack_bf2(v1[2]+bV1, v1[3]+bV1);
      }
      __syncthreads();   // K/Vt visible to all waves

      // ---- QK^T (causal tile skip) + softmax (exp2 domain, Q pre-scaled) ----
      short8 aq = *(const short8*)(sQP + arow*SQS + quad*8);
      f32x4 sc[8];
      #pragma unroll
      for (int t = 0; t < 8; t++){
        sc[t] = (f32x4){0.f,0.f,0.f,0.f};
        if (t <= wv){
          short8 bk = *(const short8*)(sK + (t*16 + c)*SQS + quad*8);
          f32x4 z = {0,0,0,0};
          sc[t] = mfma16(aq, bk, z);
        }
      }
      float rnorm[4];
      #pragma unroll
      for (int j = 0; j < 4; j++){
        float mx = -3.0e38f;
        #pragma unroll
        for (int t = 0; t < 8; t++){
          if (t < wv){                            // sub-diagonal: always valid
            mx = fmaxf(mx, sc[t][j]);
          } else if (t == wv){                    // diagonal tile: in-tile mask
            float v = (c <= quad*4 + j) ? sc[t][j] : -1.0e9f;
            sc[t][j] = v;
            mx = fmaxf(mx, v);
          }
        }
        mx = rmax16(mx);
        float sum = 0.f;
        #pragma unroll
        for (int t = 0; t < 8; t++) if (t <= wv){
          float e = exp2f(sc[t][j] - mx); sc[t][j] = e; sum += e;
        }
        sum = rsum16(sum);
        rnorm[j] = rcpf(sum);                     // applied to y after PV
      }

      // ---- P@V in 32-k quarters through sQP (wave-private; Q is dead) ----
      f32x4 y0 = {0,0,0,0}, y1 = {0,0,0,0};
      auto pv_quarter = [&](int qt, f32x4 pa, f32x4 pb){
        int s0 = wv*16 + quad*4;
        #pragma unroll
        for (int j = 0; j < 4; j++){
          sQP[(s0+j)*SQS + c     ] = __float2bfloat16(pa[j]);
          sQP[(s0+j)*SQS + 16 + c] = __float2bfloat16(pb[j]);
        }
        short8 ap  = *(const short8*)(sQP + arow*SQS + quad*8);
        short8 bv0 = *(const short8*)(sVt + (c   )*SVS + qt*32 + quad*8);
        short8 bv1 = *(const short8*)(sVt + (c+16)*SVS + qt*32 + quad*8);
        y0 = mfma16(ap, bv0, y0);
        y1 = mfma16(ap, bv1, y1);
      };
      int qmax = wv >> 1;
      pv_quarter(0, sc[0], sc[1]);
      if (qmax >= 1) pv_quarter(1, sc[2], sc[3]);
      if (qmax >= 2) pv_quarter(2, sc[4], sc[5]);
      if (qmax >= 3) pv_quarter(3, sc[6], sc[7]);
      #pragma unroll
      for (int j = 0; j < 4; j++){ y0[j] *= rnorm[j]; y1[j] *= rnorm[j]; }

      { // ---- Y -> Ybuf at this head's k'-slice (guarded: 118 rows only) ----
        int s0 = wv*16 + quad*4;
        #pragma unroll
        for (int j = 0; j < 4; j++)
          if (s0 + j < SEQ)
            *(unsigned*)(Ybuf + (s0+j)*YS + h*32 + 2*c) = pack_bf2(y0[j], y1[j]);
      }
      __syncthreads();   // all reads of K/Vt done; also fences Ybuf for FC2
    }

    // ================= FC2 (once per pass) + silu + LN / readout ==========
    short8 ay[4];
    #pragma unroll
    for (int k4 = 0; k4 < 4; k4++)
      ay[k4] = *(const short8*)(Ybuf + arow*YS + k4*32 + quad*8);
    f32x4 xx[8];
    f32x4 S1 = {0,0,0,0}, S2 = {0,0,0,0}, S3 = {0,0,0,0};
    #pragma unroll 1
    for (int t = 0; t < 8; t++){
      f32x4 acc = {0,0,0,0};
      #pragma unroll
      for (int k4 = 0; k4 < 4; k4++){
        short8 bw = *(const short8*)(w2 + (t*16 + c)*128 + k4*32 + quad*8);
        acc = mfma16(ay[k4], bw, acc);
      }
      float bias = sCb[t*16 + c];
      float w3   = sCb[128 + t*16 + c];
      #pragma unroll
      for (int j = 0; j < 4; j++){
        float v = fsilu(acc[j] + bias);
        xx[t][j] = v;
        S1[j] += v; S2[j] += v*v; S3[j] += v*w3;
      }
    }
    #pragma unroll
    for (int j = 0; j < 4; j++){
      float s1 = rsum16(S1[j]), s2 = rsum16(S2[j]), s3 = rsum16(S3[j]);
      int s = wv*16 + quad*4 + j;
      if (p == 0){
        float mu  = s1 * (1.f/128.f);
        float var = fmaxf(s2 * (1.f/128.f) - mu*mu, 0.f);
        float rs  = rsqrtf(var + 1e-5f);
        if (s < SEQ){
          #pragma unroll
          for (int t = 0; t < 8; t++){
            int d = t*16 + c;
            Ybuf[s*YS + d] = __float2bfloat16((xx[t][j] - mu)*rs*sCb[256+d] + sCb[384+d]);
          }
        }
        o1[j] = s3;                        // x1 . fc3_w residual readout
      } else {
        if (c == 0 && s < SEQ) out[b*SEQ + s] = o1[j] + s3 + fc3_b[0];
      }
    }
    if (p == 0) __syncthreads();   // fence LN writes before pass-1 afr reads
  }
}

extern "C" void kernel_launch(void* const* d_in, const int* in_sizes, int n_in,
                              void* d_out, int out_size, void* d_ws, size_t ws_size,
                              hipStream_t stream){
  const float* x     = (const float*)d_in[0];
  const float* fc1_w = (const float*)d_in[1];
  const float* fc1_b = (const float*)d_in[2];
  const float* qkv_w = (const float*)d_in[3];
  const float* qkv_b = (const float*)d_in[4];
  const float* fc2_w = (const float*)d_in[5];
  const float* fc2_b = (const float*)d_in[6];
  const float* fc3_w = (const float*)d_in[7];
  const float* fc3_b = (const float*)d_in[8];
  const float* ln_g  = (const float*)d_in[9];
  const float* ln_b  = (const float*)d_in[10];

  __hip_bfloat16* wbf = (__hip_bfloat16*)d_ws;   // 65536 bf16 = 128 KB
  prep_kernel<<<256, 256, 0, stream>>>(qkv_w, fc2_w, wbf);

  const int B = in_sizes[0] / SEQ;               // 8192
  fused_kernel<<<B, 512, 0, stream>>>(x, fc1_w, fc1_b, qkv_b, fc2_b, fc3_w, fc3_b,
                                      ln_g, ln_b, wbf, (float*)d_out);
}

// Round 5
// 2538.084 us; speedup vs baseline: 2.7351x; 1.2484x over previous
//
#include <hip/hip_runtime.h>
#include <hip/hip_bf16.h>

#define SEQ 118
#define YS  136   // Ybuf stride (272 B, 16B-aligned rows)
#define SQS 40    // sQP/sK stride (80 B)
#define SVS 136   // sVt stride

typedef __attribute__((ext_vector_type(8))) short short8;
typedef __attribute__((ext_vector_type(4))) float f32x4;

__device__ __forceinline__ f32x4 mfma16(short8 a, short8 b, f32x4 c){
  return __builtin_amdgcn_mfma_f32_16x16x32_bf16(a, b, c, 0, 0, 0);
}
__device__ __forceinline__ float bfr(float x){
  return __bfloat162float(__float2bfloat16(x));
}
__device__ __forceinline__ float rcpf(float x){ return __builtin_amdgcn_rcpf(x); }
__device__ __forceinline__ float fsilu(float z){   // z*sigmoid(z), rcp+exp2 (1-ulp parts)
  return z * rcpf(1.f + exp2f(-1.442695041f * z));
}
__device__ __forceinline__ float rsum16(float v){
  v += __shfl_xor(v,1); v += __shfl_xor(v,2); v += __shfl_xor(v,4); v += __shfl_xor(v,8);
  return v;
}
__device__ __forceinline__ float rmax16(float v){
  v = fmaxf(v, __shfl_xor(v,1)); v = fmaxf(v, __shfl_xor(v,2));
  v = fmaxf(v, __shfl_xor(v,4)); v = fmaxf(v, __shfl_xor(v,8));
  return v;
}
__device__ __forceinline__ unsigned pack_bf2(float lo, float hi){
  __hip_bfloat162 h2 = __float22bfloat162_rn(float2{lo, hi});  // packed RNE cvt
  unsigned u; __builtin_memcpy(&u, &h2, 4);   // bit_cast rejected: non-trivial copy
  return u;
}

// Pre-permuted bf16 weights (verified round 7):
//  wq/wk/wv: [h][n][k], n <-> orig col d = 4n + h (input-side to_heads)
//  w2:       [n][k'], k' = h*32 + r, dh = (r>>1)+(r&1)*16, orig k = h*32 + dh
__global__ void prep_kernel(const float* __restrict__ qkv_w,
                            const float* __restrict__ fc2_w,
                            __hip_bfloat16* __restrict__ wbf){
  int i = blockIdx.x * 256 + threadIdx.x;   // 65536 total
  int seg = i >> 14;
  int r   = i & 16383;
  int row = r >> 7;
  int k   = r & 127;
  float v;
  if (seg < 3){
    int h = row >> 5, n = row & 31;
    v = qkv_w[(seg*128 + 4*n + h)*128 + k];
  } else {
    int h = k >> 5, rr = k & 31;
    int dh = (rr >> 1) + (rr & 1)*16;
    v = fc2_w[row*128 + h*32 + dh];
  }
  wbf[i] = __float2bfloat16(v);
}

// Round 15 = round-10 body EXACTLY; allocation constraint changed.
// Register-model evidence (rounds 10-14, rocprof):
//  - HIP __launch_bounds__ arg2 == MIN WORKGROUPS/CU: (512,6)->40 arch cap,
//    (512,3)->84, (512,2)->128, (512,4)->64.
//  - rocprof VGPR_Count is ARCH ONLY. At (512,2) the compiler split acc into
//    AGPRs; arch(76)+agpr(aligned) > 128 total -> 3 waves/SIMD -> 1 block/CU
//    (occupancy 46.6% -> 24.6%, dur 2650 -> 3270 us despite zero spill).
//  - At (512,4) cap-64: 2 blocks/CU but ~170 MB/dispatch scratch spill.
// Fix: amdgpu_waves_per_eu(4,4) — a TRUE allocation floor of 4 waves/SIMD,
// i.e. arch+acc <= 128 TOTAL. Natural demand ~132, so expect <=2 dword spill,
// 2 blocks/CU, no 40 B/thread scratch storm.
__global__ void
__attribute__((amdgpu_flat_work_group_size(512, 512), amdgpu_waves_per_eu(4, 4)))
fused_kernel(const float* __restrict__ x,
             const float* __restrict__ fc1_w, const float* __restrict__ fc1_b,
             const float* __restrict__ qkv_b,
             const float* __restrict__ fc2_b, const float* __restrict__ fc3_w,
             const float* __restrict__ fc3_b,
             const float* __restrict__ ln_g,  const float* __restrict__ ln_b,
             const __hip_bfloat16* __restrict__ wbf,
             float* __restrict__ out)
{
  __shared__ __align__(16) char smem[63328];
  __hip_bfloat16* Ybuf = (__hip_bfloat16*)(smem);           // 118 x 136  32096
  __hip_bfloat16* sQP  = (__hip_bfloat16*)(smem + 32096);   // 128 x 40   10240
  __hip_bfloat16* sK   = (__hip_bfloat16*)(smem + 42336);   // 128 x 40   10240
  __hip_bfloat16* sVt  = (__hip_bfloat16*)(smem + 52576);   //  32 x 136   8704
  float*          sCb  = (float*)        (smem + 61280);    // 512 f32     2048

  const __hip_bfloat16* wq  = wbf;
  const __hip_bfloat16* wk  = wbf + 16384;
  const __hip_bfloat16* wvw = wbf + 32768;
  const __hip_bfloat16* w2  = wbf + 49152;

  const int b    = blockIdx.x;
  const int tid  = threadIdx.x;
  const int wv   = tid >> 6;        // wave 0..7 -> 16-row strip
  const int lane = tid & 63;
  const int c    = lane & 15;
  const int quad = lane >> 4;
  const int arow = wv*16 + c;       // this lane's M-row for A/ay fragments

  { // sCb: fc2_b(0..127) fc3_w(128..255) ln_g(256..383) ln_b(384..511)
    int i = tid;
    if (i < 512){
      float v;
      if      (i < 128) v = fc2_b[i];
      else if (i < 256) v = fc3_w[i-128];
      else if (i < 384) v = ln_g [i-256];
      else              v = ln_b [i-384];
      sCb[i] = v;
    }
  }
  __syncthreads();

  float o1[4];

  #pragma unroll 1
  for (int p = 0; p < 2; ++p){
    // ---- A fragments for this pass (registers only) ----
    short8 afr[4];
    if (p == 0){
      float xs = (arow < SEQ) ? x[b*SEQ + arow] : 0.f;
      #pragma unroll
      for (int k4 = 0; k4 < 4; k4++){
        int d0 = k4*32 + quad*8;
        short8 fr;
        #pragma unroll
        for (int i = 0; i < 8; i++){
          float z = xs * fc1_w[d0+i] + fc1_b[d0+i];
          float v = fsilu(z);
          if (arow >= SEQ) v = 0.f;             // pad rows exact zero
          fr[i] = (short)__builtin_bit_cast(unsigned short, __float2bfloat16(v));
        }
        afr[k4] = fr;
      }
    } else {
      #pragma unroll
      for (int k4 = 0; k4 < 4; k4++){
        short8 fr = *(const short8*)(Ybuf + arow*YS + k4*32 + quad*8);
        if (arow >= SEQ) fr = (short8){0,0,0,0,0,0,0,0};  // NaN guard for V path
        afr[k4] = fr;
      }
    }

    #pragma unroll 1
    for (int h = 0; h < 4; ++h){
      const float invf = exp2f((float)(4*c + h) * (-0.20762050593045f)); // 10000^(-d/64)

      { // ---- Q & K head GEMMs + RoPE -> sQP / sK (packed pair k-order) ----
        // Q written pre-scaled by KSC = 1/sqrt(32)/ln2: softmax is pure exp2.
        const __hip_bfloat16* wpq = wq + (h*32 + c)*128 + quad*8;
        const __hip_bfloat16* wpk = wk + (h*32 + c)*128 + quad*8;
        f32x4 q0={0,0,0,0}, q1={0,0,0,0}, k0={0,0,0,0}, k1={0,0,0,0};
        #pragma unroll
        for (int k4 = 0; k4 < 4; k4++){
          short8 bq0 = *(const short8*)(wpq + k4*32);
          short8 bq1 = *(const short8*)(wpq + 2048 + k4*32);
          short8 bk0 = *(const short8*)(wpk + k4*32);
          short8 bk1 = *(const short8*)(wpk + 2048 + k4*32);
          q0 = mfma16(afr[k4], bq0, q0);
          q1 = mfma16(afr[k4], bq1, q1);
          k0 = mfma16(afr[k4], bk0, k0);
          k1 = mfma16(afr[k4], bk1, k1);
        }
        const float KSC = 0.25500526963f;   // (1/sqrt(32)) * (1/ln2)
        float bQ0 = qkv_b[      4*c + h], bQ1 = qkv_b[ 64 + 4*c + h];
        float bK0 = qkv_b[128 + 4*c + h], bK1 = qkv_b[192 + 4*c + h];
        #pragma unroll
        for (int j = 0; j < 4; j++){
          int s = wv*16 + quad*4 + j;
          float ang = (float)s * invf;
          float cv = bfr(__cosf(ang)), sv = bfr(__sinf(ang));
          float cvq = cv*KSC, svq = sv*KSC;
          float xq1 = q0[j] + bQ0, xq2 = q1[j] + bQ1;
          float xk1 = k0[j] + bK0, xk2 = k1[j] + bK1;
          *(unsigned*)(sQP + s*SQS + 2*c) = pack_bf2( xq1*cvq + xq2*svq, -xq1*svq + xq2*cvq);
          *(unsigned*)(sK  + s*SQS + 2*c) = pack_bf2( xk1*cv  + xk2*sv , -xk1*sv  + xk2*cv );
        }
      }
      { // ---- V head GEMM -> transposed sVt[dh][s] ----
        const __hip_bfloat16* wpv = wvw + (h*32 + c)*128 + quad*8;
        f32x4 v0={0,0,0,0}, v1={0,0,0,0};
        #pragma unroll
        for (int k4 = 0; k4 < 4; k4++){
          short8 b0 = *(const short8*)(wpv + k4*32);
          short8 b1 = *(const short8*)(wpv + 2048 + k4*32);
          v0 = mfma16(afr[k4], b0, v0);
          v1 = mfma16(afr[k4], b1, v1);
        }
        float bV0 = qkv_b[256 + 4*c + h], bV1 = qkv_b[320 + 4*c + h];
        int s0 = wv*16 + quad*4;
        *(unsigned*)(sVt + (c   )*SVS + s0    ) = pack_bf2(v0[0]+bV0, v0[1]+bV0);
        *(unsigned*)(sVt + (c   )*SVS + s0 + 2) = pack_bf2(v0[2]+bV0, v0[3]+bV0);
        *(unsigned*)(sVt + (c+16)*SVS + s0    ) = pack_bf2(v1[0]+bV1, v1[1]+bV1);
        *(unsigned*)(sVt + (c+16)*SVS + s0 + 2) = pack_bf2(v1[2]+bV1, v1[3]+bV1);
      }
      __syncthreads();   // K/Vt visible to all waves

      // ---- QK^T (causal tile skip) + softmax (exp2 domain, Q pre-scaled) ----
      short8 aq = *(const short8*)(sQP + arow*SQS + quad*8);
      f32x4 sc[8];
      #pragma unroll
      for (int t = 0; t < 8; t++){
        sc[t] = (f32x4){0.f,0.f,0.f,0.f};
        if (t <= wv){
          short8 bk = *(const short8*)(sK + (t*16 + c)*SQS + quad*8);
          f32x4 z = {0,0,0,0};
          sc[t] = mfma16(aq, bk, z);
        }
      }
      float rnorm[4];
      #pragma unroll
      for (int j = 0; j < 4; j++){
        float mx = -3.0e38f;
        #pragma unroll
        for (int t = 0; t < 8; t++){
          if (t < wv){                            // sub-diagonal: always valid
            mx = fmaxf(mx, sc[t][j]);
          } else if (t == wv){                    // diagonal tile: in-tile mask
            float v = (c <= quad*4 + j) ? sc[t][j] : -1.0e9f;
            sc[t][j] = v;
            mx = fmaxf(mx, v);
          }
        }
        mx = rmax16(mx);
        float sum = 0.f;
        #pragma unroll
        for (int t = 0; t < 8; t++) if (t <= wv){
          float e = exp2f(sc[t][j] - mx); sc[t][j] = e; sum += e;
        }
        sum = rsum16(sum);
        rnorm[j] = rcpf(sum);                     // applied to y after PV
      }

      // ---- P@V in 32-k quarters through sQP (wave-private; Q is dead) ----
      f32x4 y0 = {0,0,0,0}, y1 = {0,0,0,0};
      auto pv_quarter = [&](int qt, f32x4 pa, f32x4 pb){
        int s0 = wv*16 + quad*4;
        #pragma unroll
        for (int j = 0; j < 4; j++){
          sQP[(s0+j)*SQS + c     ] = __float2bfloat16(pa[j]);
          sQP[(s0+j)*SQS + 16 + c] = __float2bfloat16(pb[j]);
        }
        short8 ap  = *(const short8*)(sQP + arow*SQS + quad*8);
        short8 bv0 = *(const short8*)(sVt + (c   )*SVS + qt*32 + quad*8);
        short8 bv1 = *(const short8*)(sVt + (c+16)*SVS + qt*32 + quad*8);
        y0 = mfma16(ap, bv0, y0);
        y1 = mfma16(ap, bv1, y1);
      };
      int qmax = wv >> 1;
      pv_quarter(0, sc[0], sc[1]);
      if (qmax >= 1) pv_quarter(1, sc[2], sc[3]);
      if (qmax >= 2) pv_quarter(2, sc[4], sc[5]);
      if (qmax >= 3) pv_quarter(3, sc[6], sc[7]);
      #pragma unroll
      for (int j = 0; j < 4; j++){ y0[j] *= rnorm[j]; y1[j] *= rnorm[j]; }

      { // ---- Y -> Ybuf at this head's k'-slice (guarded: 118 rows only) ----
        int s0 = wv*16 + quad*4;
        #pragma unroll
        for (int j = 0; j < 4; j++)
          if (s0 + j < SEQ)
            *(unsigned*)(Ybuf + (s0+j)*YS + h*32 + 2*c) = pack_bf2(y0[j], y1[j]);
      }
      __syncthreads();   // all reads of K/Vt done; also fences Ybuf for FC2
    }

    // ================= FC2 (once per pass) + silu + LN / readout ==========
    short8 ay[4];
    #pragma unroll
    for (int k4 = 0; k4 < 4; k4++)
      ay[k4] = *(const short8*)(Ybuf + arow*YS + k4*32 + quad*8);
    f32x4 xx[8];
    f32x4 S1 = {0,0,0,0}, S2 = {0,0,0,0}, S3 = {0,0,0,0};
    #pragma unroll 1
    for (int t = 0; t < 8; t++){
      f32x4 acc = {0,0,0,0};
      #pragma unroll
      for (int k4 = 0; k4 < 4; k4++){
        short8 bw = *(const short8*)(w2 + (t*16 + c)*128 + k4*32 + quad*8);
        acc = mfma16(ay[k4], bw, acc);
      }
      float bias = sCb[t*16 + c];
      float w3   = sCb[128 + t*16 + c];
      #pragma unroll
      for (int j = 0; j < 4; j++){
        float v = fsilu(acc[j] + bias);
        xx[t][j] = v;
        S1[j] += v; S2[j] += v*v; S3[j] += v*w3;
      }
    }
    #pragma unroll
    for (int j = 0; j < 4; j++){
      float s1 = rsum16(S1[j]), s2 = rsum16(S2[j]), s3 = rsum16(S3[j]);
      int s = wv*16 + quad*4 + j;
      if (p == 0){
        float mu  = s1 * (1.f/128.f);
        float var = fmaxf(s2 * (1.f/128.f) - mu*mu, 0.f);
        float rs  = rsqrtf(var + 1e-5f);
        if (s < SEQ){
          #pragma unroll
          for (int t = 0; t < 8; t++){
            int d = t*16 + c;
            Ybuf[s*YS + d] = __float2bfloat16((xx[t][j] - mu)*rs*sCb[256+d] + sCb[384+d]);
          }
        }
        o1[j] = s3;                        // x1 . fc3_w residual readout
      } else {
        if (c == 0 && s < SEQ) out[b*SEQ + s] = o1[j] + s3 + fc3_b[0];
      }
    }
    if (p == 0) __syncthreads();   // fence LN writes before pass-1 afr reads
  }
}

extern "C" void kernel_launch(void* const* d_in, const int* in_sizes, int n_in,
                              void* d_out, int out_size, void* d_ws, size_t ws_size,
                              hipStream_t stream){
  const float* x     = (const float*)d_in[0];
  const float* fc1_w = (const float*)d_in[1];
  const float* fc1_b = (const float*)d_in[2];
  const float* qkv_w = (const float*)d_in[3];
  const float* qkv_b = (const float*)d_in[4];
  const float* fc2_w = (const float*)d_in[5];
  const float* fc2_b = (const float*)d_in[6];
  const float* fc3_w = (const float*)d_in[7];
  const float* fc3_b = (const float*)d_in[8];
  const float* ln_g  = (const float*)d_in[9];
  const float* ln_b  = (const float*)d_in[10];

  __hip_bfloat16* wbf = (__hip_bfloat16*)d_ws;   // 65536 bf16 = 128 KB
  prep_kernel<<<256, 256, 0, stream>>>(qkv_w, fc2_w, wbf);

  const int B = in_sizes[0] / SEQ;               // 8192
  fused_kernel<<<B, 512, 0, stream>>>(x, fc1_w, fc1_b, qkv_b, fc2_b, fc3_w, fc3_b,
                                      ln_g, ln_b, wbf, (float*)d_out);
}